// Round 1
// baseline (499.174 us; speedup 1.0000x reference)
//
#include <hip/hip_runtime.h>
#include <hip/hip_bf16.h>

// LSTM encoder: B=4096, L=512, M=H=17.
// Strategy: 256 blocks x 16 batch, 5 waves/block (one 16x16 N-tile each).
// gates(80x16) = W'(80x64) . [x|h](64x16) via mfma_f32_16x16x32_bf16 (2 K-blocks),
// bias as C operand. Weight rows interleaved row=4*j+type so each lane's 4 acc
// regs are (i,f,g,o) for one j -> lane-local epilogue, c in a single register.
//
// R1 change vs baseline: per-step __syncthreads() replaced with raw s_barrier +
// s_waitcnt lgkmcnt(0). __syncthreads() forces the compiler to emit
// s_waitcnt vmcnt(0) before s_barrier, which puts the per-step global h store's
// HBM write-ack (~300-500 cy) on the serial recurrence path, 512 times.
// Cross-wave correctness only needs LDS (h_s/x_s) ordering -> lgkmcnt-only drain.

namespace {
constexpr int B_TOT = 4096;
constexpr int L_SEQ = 512;
constexpr int NF    = 17;                    // features == hidden
constexpr int BS    = 16;                    // batch per block
constexpr int TPB   = 320;                   // 5 waves
constexpr int TC    = 32;                    // timesteps per staged chunk
constexpr int NCHUNK = L_SEQ / TC;           // 16
constexpr int KPAD  = 24;                    // k-pad for x_s/h_s rows (quads 0..2)
constexpr int F4_PER_ROW   = TC * NF / 4;    // 136 float4 per batch-row chunk
constexpr int F4_PER_CHUNK = BS * F4_PER_ROW;// 2176
constexpr int PF_MAX = (F4_PER_CHUNK + TPB - 1) / TPB;  // 7

constexpr int OUT_H = B_TOT * L_SEQ * NF;    // 35,651,584
constexpr int OUT_C = OUT_H + B_TOT * NF;
constexpr int OUT_X = OUT_C + B_TOT * NF;
}

typedef __attribute__((ext_vector_type(8))) short bf16x8;
typedef __attribute__((ext_vector_type(4))) float f32x4;

__device__ __forceinline__ unsigned short f2bf(float f) {
  union { float f; unsigned int u; } v; v.f = f;
  unsigned int r = v.u + 0x7fff + ((v.u >> 16) & 1);   // RNE
  return (unsigned short)(r >> 16);
}
__device__ __forceinline__ float sigm(float x) {
  return __builtin_amdgcn_rcpf(1.f + __expf(-x));
}
__device__ __forceinline__ float tanh_fast(float x) {
  float e = __expf(2.f * x);                 // exp overflow -> inf -> rcp -> 0: safe
  return 1.f - 2.f * __builtin_amdgcn_rcpf(e + 1.f);
}

// Barrier that orders LDS only: drain lgkmcnt, leave vmcnt (global stores /
// prefetch loads) in flight. asm memory clobbers pin LDS ops on both sides.
__device__ __forceinline__ void block_sync_lds() {
  asm volatile("s_waitcnt lgkmcnt(0)" ::: "memory");
  __builtin_amdgcn_s_barrier();
  asm volatile("" ::: "memory");
}

__global__ void __launch_bounds__(TPB) lstm_kernel(
    const float* __restrict__ x, const float* __restrict__ W_ih,
    const float* __restrict__ W_hh, const float* __restrict__ b_ih,
    const float* __restrict__ b_hh, float* __restrict__ out)
{
  __shared__ __align__(16) unsigned short x_s[2][TC][BS][KPAD]; // bf16 bits, 48 KiB
  __shared__ __align__(16) unsigned short h_s[2][BS][KPAD];     // bf16 bits
  __shared__ __align__(16) unsigned short w0_s[80][32];         // W_ih', interleaved rows
  __shared__ __align__(16) unsigned short w1_s[80][32];         // W_hh'
  __shared__ __align__(16) float bias_s[80];
  __shared__ __align__(16) unsigned short zero16[8];            // zero frag for quad 3

  const int tid  = threadIdx.x;
  const int lane = tid & 63;
  const int T    = tid >> 6;        // wave id == N-tile id
  const int bb   = lane & 15;       // batch within block (B-frag n, C col)
  const int q    = lane >> 4;       // quad (k-octet for A/B frags, row-quad for C)
  const int b0   = blockIdx.x * BS;

  // ---- prefetch chunk 0 into registers (issue ASAP)
  f32x4 pf[PF_MAX];
  #pragma unroll
  for (int i = 0; i < PF_MAX; ++i) {
    int u = tid + TPB * i;
    if (u < F4_PER_CHUNK) {
      int row = u / F4_PER_ROW, off = u % F4_PER_ROW;
      pf[i] = *(const f32x4*)(x + ((b0 + row) * L_SEQ) * NF + off * 4);
    }
  }

  // ---- zero LDS (x_s pads persist; h0=c0=0)
  {
    unsigned int* p = (unsigned int*)&x_s[0][0][0][0];
    for (int u = tid; u < (int)(sizeof(x_s) / 4); u += TPB) p[u] = 0;
    unsigned int* ph = (unsigned int*)&h_s[0][0][0];
    for (int u = tid; u < (int)(sizeof(h_s) / 4); u += TPB) ph[u] = 0;
    if (tid < 4) ((unsigned int*)zero16)[tid] = 0;
  }
  // ---- build interleaved weight tiles + fused bias
  for (int u = tid; u < 80 * 32; u += TPB) {
    int r = u >> 5, k = u & 31;
    unsigned short v0 = 0, v1 = 0;
    int j = -1, ty = 0;
    if (r < 64)      { j = r >> 2; ty = r & 3; }
    else if (r < 68) { j = 16;     ty = r - 64; }
    if (j >= 0 && k < NF) {
      int g = ty * NF + j;          // torch gate order i,f,g,o
      v0 = f2bf(W_ih[g * NF + k]);
      v1 = f2bf(W_hh[g * NF + k]);
    }
    w0_s[r][k] = v0; w1_s[r][k] = v1;
  }
  for (int u = tid; u < 80; u += TPB) {
    float bv = 0.f; int j = -1, ty = 0;
    if (u < 64)      { j = u >> 2; ty = u & 3; }
    else if (u < 68) { j = 16;     ty = u - 64; }
    if (j >= 0) { int g = ty * NF + j; bv = b_ih[g] + b_hh[g]; }
    bias_s[u] = bv;
  }
  __syncthreads();   // zero-init & weights visible before staging/frag reads

  // ---- stage helper: write pf (chunk cn) to x_s[cn&1] + passthrough x copy
  auto stage = [&](int cn) {
    #pragma unroll
    for (int i = 0; i < PF_MAX; ++i) {
      int u = tid + TPB * i;
      if (u < F4_PER_CHUNK) {
        int row = u / F4_PER_ROW, off = u % F4_PER_ROW;
        int gidx = ((b0 + row) * L_SEQ + cn * TC) * NF + off * 4;
        *(f32x4*)(out + OUT_X + gidx) = pf[i];
        int p = off * 4, tl = p / NF, m = p - tl * NF;
        #pragma unroll
        for (int e = 0; e < 4; ++e) {
          x_s[cn & 1][tl][row][m] = f2bf(pf[i][e]);
          if (++m == NF) { m = 0; ++tl; }
        }
      }
    }
  };
  auto prefetch = [&](int cn) {
    #pragma unroll
    for (int i = 0; i < PF_MAX; ++i) {
      int u = tid + TPB * i;
      if (u < F4_PER_CHUNK) {
        int row = u / F4_PER_ROW, off = u % F4_PER_ROW;
        pf[i] = *(const f32x4*)(x + ((b0 + row) * L_SEQ + cn * TC) * NF + off * 4);
      }
    }
  };

  stage(0);        // writes buf 0; visible after first in-loop barrier
  prefetch(1);

  // ---- per-wave constant fragments (weights + bias), per-lane pointers
  const bf16x8 a0 = *(const bf16x8*)&w0_s[16 * T + bb][q * 8];
  const bf16x8 a1 = *(const bf16x8*)&w1_s[16 * T + bb][q * 8];
  const f32x4 bias4 = *(const f32x4*)&bias_s[16 * T + q * 4];

  const int j = 4 * T + q;                       // hidden index owned by this lane
  const bool active = (T < 4) || (q == 0);       // tile 4: only j=16 (quad 0) real
  const int jj = (j > 16) ? 16 : j;              // clamp for safe address formation

  const unsigned short* xbuf[2] = {
    (q == 3) ? zero16 : &x_s[0][0][bb][q * 8],
    (q == 3) ? zero16 : &x_s[1][0][bb][q * 8] };
  const int xstep = (q == 3) ? 0 : BS * KPAD;    // ushorts per timestep
  const unsigned short* hr[2] = {
    (q == 3) ? zero16 : &h_s[0][bb][q * 8],
    (q == 3) ? zero16 : &h_s[1][bb][q * 8] };
  unsigned short* hw[2] = { &h_s[1][bb][jj], &h_s[0][bb][jj] };  // write buf (t+1)&1

  float c_st = 0.f, h_last = 0.f;
  float* outp = out + (b0 + bb) * L_SEQ * NF + jj;

  // ---- main recurrence
  for (int c = 0; c < NCHUNK; ++c) {
    const unsigned short* xp = xbuf[c & 1];
    for (int tt = 0; tt < TC; ++tt) {
      const int t = c * TC + tt;
      block_sync_lds();                          // h_s[t&1] & staged x_s ready (LDS-only drain)
      bf16x8 bx = *(const bf16x8*)xp;
      bf16x8 bh = *(const bf16x8*)hr[t & 1];
      xp += xstep;
      f32x4 acc = __builtin_amdgcn_mfma_f32_16x16x32_bf16(a0, bx, bias4, 0, 0, 0);
      acc       = __builtin_amdgcn_mfma_f32_16x16x32_bf16(a1, bh, acc,   0, 0, 0);
      if (active) {
        float gi = sigm(acc[0]);
        float gf = sigm(acc[1]);
        float gg = tanh_fast(acc[2]);
        float go = sigm(acc[3]);
        c_st  = gf * c_st + gi * gg;
        h_last = go * tanh_fast(c_st);
        *hw[t & 1] = f2bf(h_last);
        outp[0] = h_last;                        // fire-and-forget: no longer drained per step
        outp += NF;
      }
    }
    if (c + 1 < NCHUNK) {
      stage(c + 1);                              // other x buffer: no race with step 31
      if (c + 2 < NCHUNK) prefetch(c + 2);
    }
  }

  // ---- final states
  if (active) {
    out[OUT_H + (b0 + bb) * NF + j] = h_last;
    out[OUT_C + (b0 + bb) * NF + j] = c_st;
  }
}

extern "C" void kernel_launch(void* const* d_in, const int* in_sizes, int n_in,
                              void* d_out, int out_size, void* d_ws, size_t ws_size,
                              hipStream_t stream) {
  (void)in_sizes; (void)n_in; (void)out_size; (void)d_ws; (void)ws_size;
  const float* x    = (const float*)d_in[0];
  const float* W_ih = (const float*)d_in[1];
  const float* W_hh = (const float*)d_in[2];
  const float* b_ih = (const float*)d_in[3];
  const float* b_hh = (const float*)d_in[4];
  float* out = (float*)d_out;
  hipLaunchKernelGGL(lstm_kernel, dim3(B_TOT / BS), dim3(TPB), 0, stream,
                     x, W_ih, W_hh, b_ih, b_hh, out);
}

// Round 2
// 465.899 us; speedup vs baseline: 1.0714x; 1.0714x over previous
//
#include <hip/hip_runtime.h>
#include <hip/hip_bf16.h>

// LSTM encoder: B=4096, L=512, M=H=17.
// Strategy: 256 blocks x 16 batch, 5 waves/block (one 16x16 N-tile each).
// gates(80x16) = W'(80x64) . [x|h](64x16) via mfma_f32_16x16x32_bf16,
// bias as C operand. Weight rows interleaved row=4*j+type so each lane's 4 acc
// regs are (i,f,g,o) for one j -> lane-local epilogue, c in a single register.
//
// R2 changes (chain surgery on the serial recurrence):
//  - Parity-unrolled timestep loop (tt += 2): every LDS pointer is a distinct
//    named scalar fixed at compile time. The old hr[t&1]/hw[t&1]/xbuf[c&1]
//    runtime-indexed arrays risked scratch demotion / per-step select chains
//    in the 512-iteration serial loop (rule #20).
//  - x-projection MFMA pipelined one step ahead (accx = mfma(a0,bx,bias4)
//    issued during the previous step's epilogue shadow): exactly ONE MFMA on
//    the h->h recurrence chain. Identical op order -> bit-identical result.
//  - h f32->bf16 via v_cvt_pk_bf16_f32 (1 instr, RNE) instead of 4-op bit math.

namespace {
constexpr int B_TOT = 4096;
constexpr int L_SEQ = 512;
constexpr int NF    = 17;                    // features == hidden
constexpr int BS    = 16;                    // batch per block
constexpr int TPB   = 320;                   // 5 waves
constexpr int TC    = 32;                    // timesteps per staged chunk
constexpr int NCHUNK = L_SEQ / TC;           // 16
constexpr int KPAD  = 24;                    // k-pad for x_s/h_s rows (quads 0..2)
constexpr int F4_PER_ROW   = TC * NF / 4;    // 136 float4 per batch-row chunk
constexpr int F4_PER_CHUNK = BS * F4_PER_ROW;// 2176
constexpr int PF_MAX = (F4_PER_CHUNK + TPB - 1) / TPB;  // 7

constexpr int OUT_H = B_TOT * L_SEQ * NF;    // 35,651,584
constexpr int OUT_C = OUT_H + B_TOT * NF;
constexpr int OUT_X = OUT_C + B_TOT * NF;
}

typedef __attribute__((ext_vector_type(8))) short bf16x8;
typedef __attribute__((ext_vector_type(4))) float f32x4;

__device__ __forceinline__ unsigned short f2bf(float f) {
  union { float f; unsigned int u; } v; v.f = f;
  unsigned int r = v.u + 0x7fff + ((v.u >> 16) & 1);   // RNE
  return (unsigned short)(r >> 16);
}
// Single-instruction f32->bf16 (RNE). gfx950-verified (learn_hip T12 recipe).
__device__ __forceinline__ unsigned short h2bf(float f) {
  unsigned int r;
  asm("v_cvt_pk_bf16_f32 %0, %1, %2" : "=v"(r) : "v"(f), "v"(f));
  return (unsigned short)r;
}
__device__ __forceinline__ float sigm(float x) {
  return __builtin_amdgcn_rcpf(1.f + __expf(-x));
}
__device__ __forceinline__ float tanh_fast(float x) {
  float e = __expf(2.f * x);                 // exp overflow -> inf -> rcp -> 0: safe
  return 1.f - 2.f * __builtin_amdgcn_rcpf(e + 1.f);
}

// LDS-only barrier: order h_s/x_s handoff without draining vmem queues.
__device__ __forceinline__ void block_sync_lds() {
  asm volatile("s_waitcnt lgkmcnt(0)" ::: "memory");
  __builtin_amdgcn_s_barrier();
  asm volatile("" ::: "memory");
}

__global__ void __launch_bounds__(TPB) lstm_kernel(
    const float* __restrict__ x, const float* __restrict__ W_ih,
    const float* __restrict__ W_hh, const float* __restrict__ b_ih,
    const float* __restrict__ b_hh, float* __restrict__ out)
{
  __shared__ __align__(16) unsigned short x_s[2][TC][BS][KPAD]; // bf16 bits, 48 KiB
  __shared__ __align__(16) unsigned short h_s[2][BS][KPAD];     // bf16 bits
  __shared__ __align__(16) unsigned short w0_s[80][32];         // W_ih', interleaved rows
  __shared__ __align__(16) unsigned short w1_s[80][32];         // W_hh'
  __shared__ __align__(16) float bias_s[80];
  __shared__ __align__(16) unsigned short zero16[8];            // zero frag for quad 3

  const int tid  = threadIdx.x;
  const int lane = tid & 63;
  const int T    = tid >> 6;        // wave id == N-tile id
  const int bb   = lane & 15;       // batch within block (B-frag n, C col)
  const int q    = lane >> 4;       // quad (k-octet for A/B frags, row-quad for C)
  const int b0   = blockIdx.x * BS;

  // ---- prefetch chunk 0 into registers (issue ASAP)
  f32x4 pf[PF_MAX];
  #pragma unroll
  for (int i = 0; i < PF_MAX; ++i) {
    int u = tid + TPB * i;
    if (u < F4_PER_CHUNK) {
      int row = u / F4_PER_ROW, off = u % F4_PER_ROW;
      pf[i] = *(const f32x4*)(x + ((b0 + row) * L_SEQ) * NF + off * 4);
    }
  }

  // ---- zero LDS (x_s pads persist; h0=c0=0)
  {
    unsigned int* p = (unsigned int*)&x_s[0][0][0][0];
    for (int u = tid; u < (int)(sizeof(x_s) / 4); u += TPB) p[u] = 0;
    unsigned int* ph = (unsigned int*)&h_s[0][0][0];
    for (int u = tid; u < (int)(sizeof(h_s) / 4); u += TPB) ph[u] = 0;
    if (tid < 4) ((unsigned int*)zero16)[tid] = 0;
  }
  // ---- build interleaved weight tiles + fused bias
  for (int u = tid; u < 80 * 32; u += TPB) {
    int r = u >> 5, k = u & 31;
    unsigned short v0 = 0, v1 = 0;
    int j = -1, ty = 0;
    if (r < 64)      { j = r >> 2; ty = r & 3; }
    else if (r < 68) { j = 16;     ty = r - 64; }
    if (j >= 0 && k < NF) {
      int g = ty * NF + j;          // torch gate order i,f,g,o
      v0 = f2bf(W_ih[g * NF + k]);
      v1 = f2bf(W_hh[g * NF + k]);
    }
    w0_s[r][k] = v0; w1_s[r][k] = v1;
  }
  for (int u = tid; u < 80; u += TPB) {
    float bv = 0.f; int j = -1, ty = 0;
    if (u < 64)      { j = u >> 2; ty = u & 3; }
    else if (u < 68) { j = 16;     ty = u - 64; }
    if (j >= 0) { int g = ty * NF + j; bv = b_ih[g] + b_hh[g]; }
    bias_s[u] = bv;
  }
  __syncthreads();   // zero-init & weights visible before staging/frag reads

  // ---- stage helper: write pf (chunk cn) to x_s[cn&1] + passthrough x copy
  auto stage = [&](int cn) {
    #pragma unroll
    for (int i = 0; i < PF_MAX; ++i) {
      int u = tid + TPB * i;
      if (u < F4_PER_CHUNK) {
        int row = u / F4_PER_ROW, off = u % F4_PER_ROW;
        int gidx = ((b0 + row) * L_SEQ + cn * TC) * NF + off * 4;
        *(f32x4*)(out + OUT_X + gidx) = pf[i];
        int p = off * 4, tl = p / NF, m = p - tl * NF;
        #pragma unroll
        for (int e = 0; e < 4; ++e) {
          x_s[cn & 1][tl][row][m] = f2bf(pf[i][e]);
          if (++m == NF) { m = 0; ++tl; }
        }
      }
    }
  };
  auto prefetch = [&](int cn) {
    #pragma unroll
    for (int i = 0; i < PF_MAX; ++i) {
      int u = tid + TPB * i;
      if (u < F4_PER_CHUNK) {
        int row = u / F4_PER_ROW, off = u % F4_PER_ROW;
        pf[i] = *(const f32x4*)(x + ((b0 + row) * L_SEQ + cn * TC) * NF + off * 4);
      }
    }
  };

  stage(0);        // writes buf 0; visible after first in-loop barrier
  prefetch(1);

  // ---- per-wave constant fragments (weights + bias), per-lane pointers
  const bf16x8 a0 = *(const bf16x8*)&w0_s[16 * T + bb][q * 8];
  const bf16x8 a1 = *(const bf16x8*)&w1_s[16 * T + bb][q * 8];
  const f32x4 bias4 = *(const f32x4*)&bias_s[16 * T + q * 4];

  const int j = 4 * T + q;                       // hidden index owned by this lane
  const bool active = (T < 4) || (q == 0);       // tile 4: only j=16 (quad 0) real
  const int jj = (j > 16) ? 16 : j;              // clamp for safe address formation

  // All LDS pointers as distinct named scalars (no runtime-indexed arrays).
  const unsigned short* const xbase0 = (q == 3) ? zero16 : &x_s[0][0][bb][q * 8];
  const unsigned short* const xbase1 = (q == 3) ? zero16 : &x_s[1][0][bb][q * 8];
  const int xstep = (q == 3) ? 0 : BS * KPAD;    // ushorts per timestep
  const unsigned short* const hr0 = (q == 3) ? zero16 : &h_s[0][bb][q * 8]; // read, even t
  const unsigned short* const hr1 = (q == 3) ? zero16 : &h_s[1][bb][q * 8]; // read, odd t
  unsigned short* const hw0 = &h_s[1][bb][jj];   // write target after even t
  unsigned short* const hw1 = &h_s[0][bb][jj];   // write target after odd t

  float c_st = 0.f, h_last = 0.f;
  float* outp = out + (b0 + bb) * L_SEQ * NF + jj;

  auto epilogue = [&](const f32x4& acc, unsigned short* hwp) {
    if (active) {
      float gi = sigm(acc[0]);
      float gf = sigm(acc[1]);
      float gg = tanh_fast(acc[2]);
      float go = sigm(acc[3]);
      c_st   = gf * c_st + gi * gg;
      h_last = go * tanh_fast(c_st);
      *hwp = h2bf(h_last);                       // get h into LDS ASAP
      outp[0] = h_last;                          // fire-and-forget global store
      outp += NF;
    }
  };

  f32x4 accx_e{}, accx_o{};                      // pipelined x-projection accs

  // ---- main recurrence (pairs of timesteps; all parity compile-time)
  for (int c = 0; c < NCHUNK; ++c) {
    const unsigned short* xp = (c & 1) ? xbase1 : xbase0;
    #pragma unroll
    for (int tt = 0; tt < TC; tt += 2) {
      // ---- even step t: read h_s[0], write h_s[1]
      block_sync_lds();                          // staged x_s & h ready
      if (tt == 0) {                             // chunk boundary: x-proj inline
        bf16x8 bx = *(const bf16x8*)xp;
        accx_e = __builtin_amdgcn_mfma_f32_16x16x32_bf16(a0, bx, bias4, 0, 0, 0);
      }
      {
        bf16x8 bh = *(const bf16x8*)hr0;
        f32x4 acc = __builtin_amdgcn_mfma_f32_16x16x32_bf16(a1, bh, accx_e, 0, 0, 0);
        bf16x8 bxo = *(const bf16x8*)(xp + xstep);   // x for odd step (off-chain)
        accx_o = __builtin_amdgcn_mfma_f32_16x16x32_bf16(a0, bxo, bias4, 0, 0, 0);
        epilogue(acc, hw0);
      }
      // ---- odd step t+1: read h_s[1], write h_s[0]
      block_sync_lds();
      {
        bf16x8 bh = *(const bf16x8*)hr1;
        f32x4 acc = __builtin_amdgcn_mfma_f32_16x16x32_bf16(a1, bh, accx_o, 0, 0, 0);
        if (tt + 2 < TC) {                       // x for next even step (off-chain)
          bf16x8 bxe = *(const bf16x8*)(xp + 2 * xstep);
          accx_e = __builtin_amdgcn_mfma_f32_16x16x32_bf16(a0, bxe, bias4, 0, 0, 0);
        }
        epilogue(acc, hw1);
      }
      xp += 2 * xstep;
    }
    if (c + 1 < NCHUNK) {
      stage(c + 1);                              // other x buffer: no race with step 31
      if (c + 2 < NCHUNK) prefetch(c + 2);
    }
  }

  // ---- final states
  if (active) {
    out[OUT_H + (b0 + bb) * NF + j] = h_last;
    out[OUT_C + (b0 + bb) * NF + j] = c_st;
  }
}

extern "C" void kernel_launch(void* const* d_in, const int* in_sizes, int n_in,
                              void* d_out, int out_size, void* d_ws, size_t ws_size,
                              hipStream_t stream) {
  (void)in_sizes; (void)n_in; (void)out_size; (void)d_ws; (void)ws_size;
  const float* x    = (const float*)d_in[0];
  const float* W_ih = (const float*)d_in[1];
  const float* W_hh = (const float*)d_in[2];
  const float* b_ih = (const float*)d_in[3];
  const float* b_hh = (const float*)d_in[4];
  float* out = (float*)d_out;
  hipLaunchKernelGGL(lstm_kernel, dim3(B_TOT / BS), dim3(TPB), 0, stream,
                     x, W_ih, W_hh, b_ih, b_hh, out);
}

// Round 3
// 454.733 us; speedup vs baseline: 1.0977x; 1.0246x over previous
//
#include <hip/hip_runtime.h>
#include <hip/hip_bf16.h>

// LSTM encoder: B=4096, L=512, M=H=17.
// Strategy: 256 blocks x 16 batch, 5 waves/block (one 16x16 N-tile each).
// gates(80x16) = W'(80x64) . [x|h](64x16) via mfma_f32_16x16x32_bf16,
// bias as C operand. Weight rows interleaved row=4*j+type so each lane's 4 acc
// regs are (i,f,g,o) for one j -> lane-local epilogue, c in a single register.
//
// R3 changes:
//  - Per-chunk BURST precompute of the x-projection: hist[tt] = mfma(a0,bx,bias4)
//    for all TC steps, held in registers. The per-step loop is now
//    barrier -> ds_read h -> ONE mfma (C=hist[tt]) -> epilogue -> ds_write h.
//    Removes the per-step bx ds_read + x-MFMA: under barrier lockstep all 5
//    waves hit LDS simultaneously, so halving per-step LDS traffic shortens
//    the phase-locked period directly.
//  - TC 32 -> 16 so hist fits in 64 VGPRs (no spill risk in the serial loop).
//  - Global stores forced to global_store_dword[x4] via inline asm: provably
//    vmcnt-only (no flat/lgkm interaction with the per-step barrier), and
//    free-floating (not bundled into compiler waitcnt before barriers).

namespace {
constexpr int B_TOT = 4096;
constexpr int L_SEQ = 512;
constexpr int NF    = 17;                    // features == hidden
constexpr int BS    = 16;                    // batch per block
constexpr int TPB   = 320;                   // 5 waves
constexpr int TC    = 16;                    // timesteps per staged chunk
constexpr int NCHUNK = L_SEQ / TC;           // 32
constexpr int KPAD  = 24;                    // k-pad for x_s/h_s rows (quads 0..2)
constexpr int F4_PER_ROW   = TC * NF / 4;    // 68 float4 per batch-row chunk
constexpr int F4_PER_CHUNK = BS * F4_PER_ROW;// 1088
constexpr int PF_MAX = (F4_PER_CHUNK + TPB - 1) / TPB;  // 4

constexpr int OUT_H = B_TOT * L_SEQ * NF;    // 35,651,584
constexpr int OUT_C = OUT_H + B_TOT * NF;
constexpr int OUT_X = OUT_C + B_TOT * NF;
}

typedef __attribute__((ext_vector_type(8))) short bf16x8;
typedef __attribute__((ext_vector_type(4))) float f32x4;

__device__ __forceinline__ unsigned short f2bf(float f) {
  union { float f; unsigned int u; } v; v.f = f;
  unsigned int r = v.u + 0x7fff + ((v.u >> 16) & 1);   // RNE
  return (unsigned short)(r >> 16);
}
// Single-instruction f32->bf16 (RNE).
__device__ __forceinline__ unsigned short h2bf(float f) {
  unsigned int r;
  asm("v_cvt_pk_bf16_f32 %0, %1, %2" : "=v"(r) : "v"(f), "v"(f));
  return (unsigned short)r;
}
__device__ __forceinline__ float sigm(float x) {
  return __builtin_amdgcn_rcpf(1.f + __expf(-x));
}
__device__ __forceinline__ float tanh_fast(float x) {
  float e = __expf(2.f * x);                 // exp overflow -> inf -> rcp -> 0: safe
  return 1.f - 2.f * __builtin_amdgcn_rcpf(e + 1.f);
}

// Forced-global stores: vmcnt-only, fire-and-forget, exec-masked under divergence.
__device__ __forceinline__ void gstore1(float* p, float v) {
  asm volatile("global_store_dword %0, %1, off" :: "v"(p), "v"(v));
}
__device__ __forceinline__ void gstore4(float* p, f32x4 v) {
  asm volatile("global_store_dwordx4 %0, %1, off" :: "v"(p), "v"(v));
}

// LDS-only barrier: order h_s/x_s handoff without draining vmem queues.
__device__ __forceinline__ void block_sync_lds() {
  asm volatile("s_waitcnt lgkmcnt(0)" ::: "memory");
  __builtin_amdgcn_s_barrier();
  asm volatile("" ::: "memory");
}

__global__ void __launch_bounds__(TPB) lstm_kernel(
    const float* __restrict__ x, const float* __restrict__ W_ih,
    const float* __restrict__ W_hh, const float* __restrict__ b_ih,
    const float* __restrict__ b_hh, float* __restrict__ out)
{
  __shared__ __align__(16) unsigned short x_s[2][TC][BS][KPAD]; // bf16 bits, 24 KiB
  __shared__ __align__(16) unsigned short h_s[2][BS][KPAD];     // bf16 bits
  __shared__ __align__(16) unsigned short w0_s[80][32];         // W_ih', interleaved rows
  __shared__ __align__(16) unsigned short w1_s[80][32];         // W_hh'
  __shared__ __align__(16) float bias_s[80];
  __shared__ __align__(16) unsigned short zero16[8];            // zero frag for quad 3

  const int tid  = threadIdx.x;
  const int lane = tid & 63;
  const int T    = tid >> 6;        // wave id == N-tile id
  const int bb   = lane & 15;       // batch within block (B-frag n, C col)
  const int q    = lane >> 4;       // quad (k-octet for A/B frags, row-quad for C)
  const int b0   = blockIdx.x * BS;

  // ---- prefetch chunk 0 into registers (issue ASAP)
  f32x4 pf[PF_MAX];
  #pragma unroll
  for (int i = 0; i < PF_MAX; ++i) {
    int u = tid + TPB * i;
    if (u < F4_PER_CHUNK) {
      int row = u / F4_PER_ROW, off = u % F4_PER_ROW;
      pf[i] = *(const f32x4*)(x + ((b0 + row) * L_SEQ) * NF + off * 4);
    }
  }

  // ---- zero LDS (x_s pads persist; h0=c0=0)
  {
    unsigned int* p = (unsigned int*)&x_s[0][0][0][0];
    for (int u = tid; u < (int)(sizeof(x_s) / 4); u += TPB) p[u] = 0;
    unsigned int* ph = (unsigned int*)&h_s[0][0][0];
    for (int u = tid; u < (int)(sizeof(h_s) / 4); u += TPB) ph[u] = 0;
    if (tid < 4) ((unsigned int*)zero16)[tid] = 0;
  }
  // ---- build interleaved weight tiles + fused bias
  for (int u = tid; u < 80 * 32; u += TPB) {
    int r = u >> 5, k = u & 31;
    unsigned short v0 = 0, v1 = 0;
    int j = -1, ty = 0;
    if (r < 64)      { j = r >> 2; ty = r & 3; }
    else if (r < 68) { j = 16;     ty = r - 64; }
    if (j >= 0 && k < NF) {
      int g = ty * NF + j;          // torch gate order i,f,g,o
      v0 = f2bf(W_ih[g * NF + k]);
      v1 = f2bf(W_hh[g * NF + k]);
    }
    w0_s[r][k] = v0; w1_s[r][k] = v1;
  }
  for (int u = tid; u < 80; u += TPB) {
    float bv = 0.f; int j = -1, ty = 0;
    if (u < 64)      { j = u >> 2; ty = u & 3; }
    else if (u < 68) { j = 16;     ty = u - 64; }
    if (j >= 0) { int g = ty * NF + j; bv = b_ih[g] + b_hh[g]; }
    bias_s[u] = bv;
  }
  __syncthreads();   // zero-init & weights visible before staging/frag reads

  // ---- stage helper: write pf (chunk cn) to x_s[cn&1] + passthrough x copy
  auto stage = [&](int cn) {
    #pragma unroll
    for (int i = 0; i < PF_MAX; ++i) {
      int u = tid + TPB * i;
      if (u < F4_PER_CHUNK) {
        int row = u / F4_PER_ROW, off = u % F4_PER_ROW;
        int gidx = ((b0 + row) * L_SEQ + cn * TC) * NF + off * 4;
        gstore4(out + OUT_X + gidx, pf[i]);
        int p = off * 4, tl = p / NF, m = p - tl * NF;
        #pragma unroll
        for (int e = 0; e < 4; ++e) {
          x_s[cn & 1][tl][row][m] = f2bf(pf[i][e]);
          if (++m == NF) { m = 0; ++tl; }
        }
      }
    }
  };
  auto prefetch = [&](int cn) {
    #pragma unroll
    for (int i = 0; i < PF_MAX; ++i) {
      int u = tid + TPB * i;
      if (u < F4_PER_CHUNK) {
        int row = u / F4_PER_ROW, off = u % F4_PER_ROW;
        pf[i] = *(const f32x4*)(x + ((b0 + row) * L_SEQ + cn * TC) * NF + off * 4);
      }
    }
  };

  stage(0);        // writes buf 0; visible after chunk-top barrier
  prefetch(1);

  // ---- per-wave constant fragments (weights + bias), per-lane pointers
  const bf16x8 a0 = *(const bf16x8*)&w0_s[16 * T + bb][q * 8];
  const bf16x8 a1 = *(const bf16x8*)&w1_s[16 * T + bb][q * 8];
  const f32x4 bias4 = *(const f32x4*)&bias_s[16 * T + q * 4];

  const int j = 4 * T + q;                       // hidden index owned by this lane
  const bool active = (T < 4) || (q == 0);       // tile 4: only j=16 (quad 0) real
  const int jj = (j > 16) ? 16 : j;              // clamp for safe address formation

  // All LDS pointers as distinct named scalars (no runtime-indexed arrays).
  const unsigned short* const xbase0 = (q == 3) ? zero16 : &x_s[0][0][bb][q * 8];
  const unsigned short* const xbase1 = (q == 3) ? zero16 : &x_s[1][0][bb][q * 8];
  const int xstep = (q == 3) ? 0 : BS * KPAD;    // ushorts per timestep
  const unsigned short* const hr0 = (q == 3) ? zero16 : &h_s[0][bb][q * 8]; // read, even t
  const unsigned short* const hr1 = (q == 3) ? zero16 : &h_s[1][bb][q * 8]; // read, odd t
  unsigned short* const hw0 = &h_s[1][bb][jj];   // write target after even t
  unsigned short* const hw1 = &h_s[0][bb][jj];   // write target after odd t

  float c_st = 0.f, h_last = 0.f;
  float* outp = out + (b0 + bb) * L_SEQ * NF + jj;

  auto epilogue = [&](const f32x4& acc, unsigned short* hwp) {
    if (active) {
      float gi = sigm(acc[0]);
      float gf = sigm(acc[1]);
      float gg = tanh_fast(acc[2]);
      float go = sigm(acc[3]);
      c_st   = gf * c_st + gi * gg;
      h_last = go * tanh_fast(c_st);
      *hwp = h2bf(h_last);                       // get h into LDS ASAP
      gstore1(outp, h_last);                     // forced-global, fire-and-forget
      outp += NF;
    }
  };

  // ---- main recurrence
  for (int c = 0; c < NCHUNK; ++c) {
    block_sync_lds();          // staged x_s[c&1] visible to all before burst

    // Burst: x-projection for all TC steps of this chunk into registers.
    // Off the recurrence chain; reads x_s only (h_s untouched).
    const unsigned short* xq = (c & 1) ? xbase1 : xbase0;
    f32x4 hist[TC];
    #pragma unroll
    for (int tt = 0; tt < TC; ++tt) {
      bf16x8 bx = *(const bf16x8*)(xq + tt * xstep);
      hist[tt] = __builtin_amdgcn_mfma_f32_16x16x32_bf16(a0, bx, bias4, 0, 0, 0);
    }

    // Steps: barrier -> ds_read h -> 1 MFMA -> epilogue -> ds_write h.
    #pragma unroll
    for (int tt = 0; tt < TC; tt += 2) {
      // even step t: read h_s[0], write h_s[1]
      block_sync_lds();
      {
        bf16x8 bh = *(const bf16x8*)hr0;
        f32x4 acc = __builtin_amdgcn_mfma_f32_16x16x32_bf16(a1, bh, hist[tt], 0, 0, 0);
        epilogue(acc, hw0);
      }
      // odd step t+1: read h_s[1], write h_s[0]
      block_sync_lds();
      {
        bf16x8 bh = *(const bf16x8*)hr1;
        f32x4 acc = __builtin_amdgcn_mfma_f32_16x16x32_bf16(a1, bh, hist[tt + 1], 0, 0, 0);
        epilogue(acc, hw1);
      }
    }

    if (c + 1 < NCHUNK) {
      stage(c + 1);                              // other x buffer: no race with burst/steps
      if (c + 2 < NCHUNK) prefetch(c + 2);
    }
  }

  // ---- final states
  if (active) {
    gstore1(out + OUT_H + (b0 + bb) * NF + j, h_last);
    gstore1(out + OUT_C + (b0 + bb) * NF + j, c_st);
  }
}

extern "C" void kernel_launch(void* const* d_in, const int* in_sizes, int n_in,
                              void* d_out, int out_size, void* d_ws, size_t ws_size,
                              hipStream_t stream) {
  (void)in_sizes; (void)n_in; (void)out_size; (void)d_ws; (void)ws_size;
  const float* x    = (const float*)d_in[0];
  const float* W_ih = (const float*)d_in[1];
  const float* W_hh = (const float*)d_in[2];
  const float* b_ih = (const float*)d_in[3];
  const float* b_hh = (const float*)d_in[4];
  float* out = (float*)d_out;
  hipLaunchKernelGGL(lstm_kernel, dim3(B_TOT / BS), dim3(TPB), 0, stream,
                     x, W_ih, W_hh, b_ih, b_hh, out);
}